// Round 9
// baseline (525.179 us; speedup 1.0000x reference)
//
#include <hip/hip_runtime.h>

typedef unsigned int u32;
typedef unsigned long long u64;
typedef unsigned short u16;
typedef unsigned char u8;

#define NN 100000        // nodes
#define NE 3200000       // edges
#define DIM 128
#define RB 256           // rows per bucket
#define NBK 391          // ceil(NN/RB)
#define BCAP 9216        // entries/bucket; mean 8192, sigma 90.5 -> +11.3 sigma
#define EB 8192          // edges per bin block
#define SLN (NN * 8)     // u32 per column slice (3.2 MB; fits one XCD's 4 MB L2)

// workspace layout, bytes (peak 38,834,432 <= proven 39,604,224)
#define OFF_OFFS 0              // int[NN+1] row offsets (exact CSR)
#define OFF_WB 400064           // uint4[2048]: W bf16 in MFMA B-frag tiles (32 KB)
#define OFF_BCUR 432832         // int[NBK] bucket cursors (zeroed)
#define OFF_CVP 434432          // u32[NE] CSR payload (v<<17|col), 12.8 MB
#define OFF_SH 13234432         // time-shared: staging (bin->csr) then support (gemm->fused)
#define SCV_BYTES 14417664      // NBK*BCAP*4

typedef __attribute__((ext_vector_type(8))) short bf16x8;
typedef __attribute__((ext_vector_type(4))) float f32x4;

__device__ __forceinline__ float bflo(u32 b) { return __uint_as_float(b << 16); }
__device__ __forceinline__ float bfhi(u32 b) { return __uint_as_float(b & 0xffff0000u); }
__device__ __forceinline__ u16 f2bf(float f) {
    u32 u = __float_as_uint(f);
    return (u16)((u + 0x7fffu + ((u >> 16) & 1u)) >> 16);   // RNE
}

// ---- bin: W pack + per-block LDS counting sort -> run-coalesced bucket staging ----
__global__ __launch_bounds__(256) void bin_kernel(const int4* __restrict__ erow4,
                                                  const int4* __restrict__ ecol4,
                                                  const float4* __restrict__ ev4,
                                                  int* __restrict__ bcur,
                                                  u32* __restrict__ scv,
                                                  u8* __restrict__ slr,
                                                  const float* __restrict__ wf,
                                                  uint4* __restrict__ wB4) {
    __shared__ u32 sscv[EB];        // 32 KB sorted payload
    __shared__ u32 skey[EB];        // 32 KB (bk<<8)|lr
    __shared__ int sa[512], sb[512], rs[512];   // hist + scan ping-pong + run starts
    __shared__ int base[NBK], lcur[NBK];
    int t = threadIdx.x;
    int gid = blockIdx.x * 256 + t;
    if (gid < 2048) {
        // W pack: tile = kt*8+n; lane l holds B-frag
        // elem j = W[kt*32 + (l>>4)*8 + j][n*16 + (l&15)], 8 bf16 -> uint4
        int tile = gid >> 6, l = gid & 63;
        int kt = tile >> 3, n = tile & 7;
        int col = n * 16 + (l & 15);
        int kb = kt * 32 + (l >> 4) * 8;
        u32 wp[4];
#pragma unroll
        for (int jj = 0; jj < 4; ++jj) {
            float w0 = wf[(kb + 2 * jj) * DIM + col];
            float w1 = wf[(kb + 2 * jj + 1) * DIM + col];
            wp[jj] = (u32)f2bf(w0) | ((u32)f2bf(w1) << 16);
        }
        wB4[tile * 64 + l] = make_uint4(wp[0], wp[1], wp[2], wp[3]);
    }
    int e0 = blockIdx.x * EB;
    int nval = min(EB, NE - e0);    // valid edges this block
    int4 er[8];
    bool val[8];
#pragma unroll
    for (int k = 0; k < 8; ++k) {
        int idx4 = (e0 >> 2) + k * 256 + t;
        val[k] = idx4 < NE / 4;
        er[k] = val[k] ? erow4[idx4] : make_int4(0, 0, 0, 0);
    }
    for (int i = t; i < 512; i += 256) sa[i] = 0;
    __syncthreads();
#pragma unroll
    for (int k = 0; k < 8; ++k) {
        if (val[k]) {
            atomicAdd(&sa[er[k].x >> 8], 1);
            atomicAdd(&sa[er[k].y >> 8], 1);
            atomicAdd(&sa[er[k].z >> 8], 1);
            atomicAdd(&sa[er[k].w >> 8], 1);
        }
    }
    __syncthreads();
    // reserve global runs (reads sa pre-scan; scan round 1 writes sb only, then syncs)
    for (int i = t; i < NBK; i += 256) base[i] = atomicAdd(&bcur[i], sa[i]);
    // Hillis-Steele inclusive scan over 512 (ping-pong)
    int* pa = sa; int* pb = sb;
    for (int d = 1; d < 512; d <<= 1) {
        for (int i = t; i < 512; i += 256)
            pb[i] = (i >= d) ? (pa[i] + pa[i - d]) : pa[i];
        __syncthreads();
        int* tmp = pa; pa = pb; pb = tmp;
    }
    for (int i = t; i < 512; i += 256) {
        int ex = i ? pa[i - 1] : 0;
        rs[i] = ex;
        if (i < NBK) lcur[i] = ex;
    }
    __syncthreads();
    // LDS scatter (counting-sort placement)
#pragma unroll
    for (int k = 0; k < 8; ++k) {
        if (val[k]) {
            int idx4 = (e0 >> 2) + k * 256 + t;
            int4 c = ecol4[idx4];
            float4 v = ev4[idx4];
            int r, b, pos;
            r = er[k].x; b = r >> 8; pos = atomicAdd(&lcur[b], 1);
            sscv[pos] = ((u32)f2bf(v.x) << 17) | (u32)c.x; skey[pos] = ((u32)b << 8) | (u32)(r & 255);
            r = er[k].y; b = r >> 8; pos = atomicAdd(&lcur[b], 1);
            sscv[pos] = ((u32)f2bf(v.y) << 17) | (u32)c.y; skey[pos] = ((u32)b << 8) | (u32)(r & 255);
            r = er[k].z; b = r >> 8; pos = atomicAdd(&lcur[b], 1);
            sscv[pos] = ((u32)f2bf(v.z) << 17) | (u32)c.z; skey[pos] = ((u32)b << 8) | (u32)(r & 255);
            r = er[k].w; b = r >> 8; pos = atomicAdd(&lcur[b], 1);
            sscv[pos] = ((u32)f2bf(v.w) << 17) | (u32)c.w; skey[pos] = ((u32)b << 8) | (u32)(r & 255);
        }
    }
    __syncthreads();
    // linear copy-out: consecutive i within a run -> consecutive global addresses
    for (int i = t; i < nval; i += 256) {
        u32 key = skey[i];
        int bk = key >> 8;
        int gl = base[bk] + (i - rs[bk]);
        if (gl < BCAP) {
            scv[bk * BCAP + gl] = sscv[i];
            slr[bk * BCAP + gl] = (u8)(key & 255);
        }
    }
}

// ---- csr: inline bucket-base prefix + LDS histogram/scan -> exact offs; LDS scatter ----
__global__ __launch_bounds__(256) void csr_kernel(const u32* __restrict__ scv,
                                                  const u8* __restrict__ slr,
                                                  const int* __restrict__ bcur,
                                                  int* __restrict__ offs,
                                                  u32* __restrict__ cvp) {
    __shared__ u32 lcv[BCAP];       // 36,864 B
    __shared__ int sa[RB], sb[RB], lcur[RB], red[256];
    int b = blockIdx.x, t = threadIdx.x;
    int r0 = b * RB;
    int rows = min(RB, NN - r0);
    int n = min(bcur[b], BCAP);
    // gbase = sum_{i<b} min(bcur[i],BCAP) via strided partials + tree reduce
    int p = 0;
    for (int i = t; i < b; i += 256) p += min(bcur[i], BCAP);
    red[t] = p;
    sa[t] = 0;
    __syncthreads();
    for (int d = 128; d; d >>= 1) {
        if (t < d) red[t] += red[t + d];
        __syncthreads();
    }
    int gbase = red[0];
    if (b == NBK - 1 && t == 0) offs[NN] = gbase + n;
    const u32* scvB = scv + (size_t)b * BCAP;
    const u8* slrB = slr + (size_t)b * BCAP;
    const u32* slr4 = (const u32*)slrB;     // BCAP%4==0, base 16B-aligned
    const uint4* scv4 = (const uint4*)scvB;
    int n4 = n >> 2;
    for (int i = t; i < n4; i += 256) {
        u32 w = slr4[i];
        atomicAdd(&sa[w & 255], 1);
        atomicAdd(&sa[(w >> 8) & 255], 1);
        atomicAdd(&sa[(w >> 16) & 255], 1);
        atomicAdd(&sa[w >> 24], 1);
    }
    for (int i = (n4 << 2) + t; i < n; i += 256) atomicAdd(&sa[slrB[i]], 1);
    __syncthreads();
    int* pa = sa; int* pb = sb;
    for (int d = 1; d < 256; d <<= 1) {
        pb[t] = (t >= d) ? (pa[t] + pa[t - d]) : pa[t];
        __syncthreads();
        int* tmp = pa; pa = pb; pb = tmp;
    }
    int excl = t ? pa[t - 1] : 0;
    if (t < rows) offs[r0 + t] = gbase + excl;
    lcur[t] = excl;
    __syncthreads();
    for (int i = t; i < n4; i += 256) {
        uint4 cvq = scv4[i];
        u32 w = slr4[i];
        int pos;
        pos = atomicAdd(&lcur[w & 255], 1);         lcv[pos] = cvq.x;
        pos = atomicAdd(&lcur[(w >> 8) & 255], 1);  lcv[pos] = cvq.y;
        pos = atomicAdd(&lcur[(w >> 16) & 255], 1); lcv[pos] = cvq.z;
        pos = atomicAdd(&lcur[w >> 24], 1);         lcv[pos] = cvq.w;
    }
    for (int i = (n4 << 2) + t; i < n; i += 256) {
        int pos = atomicAdd(&lcur[slrB[i]], 1);
        lcv[pos] = scvB[i];
    }
    __syncthreads();
    for (int i = t; i < n; i += 256) cvp[gbase + i] = lcv[i];
}

// ---- gemm: support = X @ W, bf16 out, SLICE-MAJOR sup[s][node][8 u32] ----
__global__ __launch_bounds__(256) void gemm_kernel(const float4* __restrict__ xf4,
                                                   const uint4* __restrict__ wB4,
                                                   u32* __restrict__ sup) {
    __shared__ u32 st[64][68];      // 64 rows x 64 col-pairs, +4 pad
    int t = threadIdx.x, wave = t >> 6, lane = t & 63;
    int l15 = lane & 15, kg = lane >> 4;
    int row = blockIdx.x * 64 + wave * 16 + l15;   // A-frag row
    int rc = min(row, NN - 1);
    f32x4 acc[8];
#pragma unroll
    for (int n = 0; n < 8; ++n) acc[n] = (f32x4){0.f, 0.f, 0.f, 0.f};
#pragma unroll
    for (int kt = 0; kt < 4; ++kt) {
        int k0 = kt * 32 + kg * 8;
        int bidx = (rc * DIM + k0) >> 2;
        float4 xa = xf4[bidx];
        float4 xc = xf4[bidx + 1];
        union { u32 u[4]; bf16x8 v; } A;
        A.u[0] = (u32)f2bf(xa.x) | ((u32)f2bf(xa.y) << 16);
        A.u[1] = (u32)f2bf(xa.z) | ((u32)f2bf(xa.w) << 16);
        A.u[2] = (u32)f2bf(xc.x) | ((u32)f2bf(xc.y) << 16);
        A.u[3] = (u32)f2bf(xc.z) | ((u32)f2bf(xc.w) << 16);
#pragma unroll
        for (int n = 0; n < 8; ++n) {
            union { uint4 u; bf16x8 v; } B;
            B.u = wB4[(kt * 8 + n) * 64 + lane];
            acc[n] = __builtin_amdgcn_mfma_f32_16x16x32_bf16(A.v, B.v, acc[n], 0, 0, 0);
        }
    }
    // C layout (m89-verified): col = lane&15, row = (lane>>4)*4 + reg
    u16* stp = (u16*)st;
    int rbase = wave * 16 + kg * 4;
#pragma unroll
    for (int n = 0; n < 8; ++n)
#pragma unroll
        for (int i = 0; i < 4; ++i)
            stp[(rbase + i) * 136 + n * 16 + l15] = f2bf(acc[n][i]);
    __syncthreads();
    int r0 = blockIdx.x * 64;
    int rmax = min(64, NN - r0);
    for (int idx = t; idx < 4096; idx += 256) {
        int r = idx >> 6, c = idx & 63;
        if (r < rmax) sup[(c >> 3) * SLN + (r0 + r) * 8 + (c & 7)] = st[r][c];
    }
}

// ---- fused: out[r] = sum_e v * support[c] + bias ; XCD-sliced gather, no shfl ----
// block b = group*8 + s: slice s -> XCD s (blockIdx%8), each XCD gathers only its
// 3.2 MB slice (L2-resident). Edge words loaded DIRECTLY per lane-group from cvp
// (8 consecutive u32 per wave, HW-merged; nt so the stream doesn't evict the slice).
// 32-edge unrolled batches: 4 independent cvp-load -> gather chains.
__global__ __launch_bounds__(256) void fused_kernel(const int* __restrict__ offs,
                                                    const u32* __restrict__ cvp,
                                                    const u32* __restrict__ sup,
                                                    const float2* __restrict__ bf2v,
                                                    u64* __restrict__ out) {
    int t = threadIdx.x;
    int wave = t >> 6, lane = t & 63;
    int bid = blockIdx.x;
    int s = bid & 7;                        // slice == target XCD
    int node = (bid >> 3) * 4 + wave;       // < NN (NN % 4 == 0)
    int e8 = lane >> 3, j = lane & 7;
    const u32* sups = sup + s * SLN;
    int start = offs[node];
    int cnt = offs[node + 1] - start;
    const u32* cv = cvp + start;
    float a0 = 0.f, a1 = 0.f;
    int k = 0;
    for (; k + 32 <= cnt; k += 32) {
        u32 p[4], xr[4];
#pragma unroll
        for (int q = 0; q < 4; ++q)
            p[q] = __builtin_nontemporal_load(&cv[k + q * 8 + e8]);
#pragma unroll
        for (int q = 0; q < 4; ++q)
            xr[q] = __hip_atomic_load(sups + (p[q] & 0x1ffffu) * 8 + j,
                                      __ATOMIC_RELAXED, __HIP_MEMORY_SCOPE_AGENT);
#pragma unroll
        for (int q = 0; q < 4; ++q) {
            float v = bflo(p[q] >> 17);
            a0 = fmaf(v, bflo(xr[q]), a0);
            a1 = fmaf(v, bfhi(xr[q]), a1);
        }
    }
    for (; k < cnt; k += 8) {
        int idx = k + e8;
        u32 p = __builtin_nontemporal_load(&cv[idx < cnt ? idx : cnt - 1]);
        if (idx >= cnt) p = 0;              // v=0, row 0 gather: adds nothing
        u32 xr = __hip_atomic_load(sups + (p & 0x1ffffu) * 8 + j,
                                   __ATOMIC_RELAXED, __HIP_MEMORY_SCOPE_AGENT);
        float v = bflo(p >> 17);
        a0 = fmaf(v, bflo(xr), a0);
        a1 = fmaf(v, bfhi(xr), a1);
    }
#pragma unroll
    for (int m = 8; m < 64; m <<= 1) {
        a0 += __shfl_xor(a0, m);
        a1 += __shfl_xor(a1, m);
    }
    if (lane < 8) {
        float2 bp = bf2v[s * 8 + j];
        u64 bits = (u64)__float_as_uint(a0 + bp.x) | ((u64)__float_as_uint(a1 + bp.y) << 32);
        __builtin_nontemporal_store(bits, &out[(size_t)node * 64 + s * 8 + j]);
    }
}

extern "C" void kernel_launch(void* const* d_in, const int* in_sizes, int n_in,
                              void* d_out, int out_size, void* d_ws, size_t ws_size,
                              hipStream_t stream) {
    const float* x = (const float*)d_in[0];
    const int* erow = (const int*)d_in[1];
    const int* ecol = (const int*)d_in[2];
    const float* ev = (const float*)d_in[3];
    const float* wf = (const float*)d_in[4];
    const float2* bf2v = (const float2*)d_in[5];

    char* ws = (char*)d_ws;
    int* offs = (int*)(ws + OFF_OFFS);
    uint4* wB4 = (uint4*)(ws + OFF_WB);
    int* bcur = (int*)(ws + OFF_BCUR);
    u32* cvp = (u32*)(ws + OFF_CVP);
    u32* scv = (u32*)(ws + OFF_SH);
    u8* slr = (u8*)(ws + OFF_SH + SCV_BYTES);
    u32* sup = (u32*)(ws + OFF_SH);   // overlays staging after csr is done

    hipMemsetAsync(bcur, 0, NBK * sizeof(int), stream);

    bin_kernel<<<(NE + EB - 1) / EB, 256, 0, stream>>>((const int4*)erow, (const int4*)ecol,
                                                       (const float4*)ev, bcur,
                                                       scv, slr, wf, wB4);
    csr_kernel<<<NBK, 256, 0, stream>>>(scv, slr, bcur, offs, cvp);
    gemm_kernel<<<(NN + 63) / 64, 256, 0, stream>>>((const float4*)x, wB4, sup);
    fused_kernel<<<(NN / 4) * 8, 256, 0, stream>>>(offs, cvp, sup, bf2v, (u64*)d_out);
}

// Round 10
// 282.648 us; speedup vs baseline: 1.8581x; 1.8581x over previous
//
#include <hip/hip_runtime.h>

typedef unsigned int u32;
typedef unsigned long long u64;
typedef unsigned short u16;
typedef unsigned char u8;

#define NN 100000        // nodes
#define NE 3200000       // edges
#define DIM 128
#define RB 256           // rows per bucket
#define NBK 391          // ceil(NN/RB)
#define BCAP 9216        // entries/bucket; mean 8192, sigma 90.5 -> +11.3 sigma
#define EB 8192          // edges per bin block

// workspace layout, bytes (peak 38,834,432 <= proven 39,604,224)
#define OFF_OFFS 0              // int[NN+1] row offsets (exact CSR)
#define OFF_WB 400064           // uint4[2048]: W bf16 in MFMA B-frag tiles (32 KB)
#define OFF_BCUR 432832         // int[NBK] bucket cursors (zeroed)
#define OFF_CVP 434432          // u32[NE] CSR payload (v<<17|col), 12.8 MB
#define OFF_SH 13234432         // time-shared: staging (bin->csr) then support (gemm->fused)
#define SCV_BYTES 14417664      // NBK*BCAP*4

typedef __attribute__((ext_vector_type(8))) short bf16x8;
typedef __attribute__((ext_vector_type(4))) float f32x4;

__device__ __forceinline__ float bflo(u32 b) { return __uint_as_float(b << 16); }
__device__ __forceinline__ float bfhi(u32 b) { return __uint_as_float(b & 0xffff0000u); }
__device__ __forceinline__ u16 f2bf(float f) {
    u32 u = __float_as_uint(f);
    return (u16)((u + 0x7fffu + ((u >> 16) & 1u)) >> 16);   // RNE
}

// ---- bin: W pack + per-block LDS counting sort -> run-coalesced bucket staging ----
__global__ __launch_bounds__(256) void bin_kernel(const int4* __restrict__ erow4,
                                                  const int4* __restrict__ ecol4,
                                                  const float4* __restrict__ ev4,
                                                  int* __restrict__ bcur,
                                                  u32* __restrict__ scv,
                                                  u8* __restrict__ slr,
                                                  const float* __restrict__ wf,
                                                  uint4* __restrict__ wB4) {
    __shared__ u32 sscv[EB];        // 32 KB sorted payload
    __shared__ u32 skey[EB];        // 32 KB (bk<<8)|lr
    __shared__ int sa[512], sb[512], rs[512];   // hist + scan ping-pong + run starts
    __shared__ int base[NBK], lcur[NBK];
    int t = threadIdx.x;
    int gid = blockIdx.x * 256 + t;
    if (gid < 2048) {
        // W pack: tile = kt*8+n; lane l holds B-frag
        // elem j = W[kt*32 + (l>>4)*8 + j][n*16 + (l&15)], 8 bf16 -> uint4
        int tile = gid >> 6, l = gid & 63;
        int kt = tile >> 3, n = tile & 7;
        int col = n * 16 + (l & 15);
        int kb = kt * 32 + (l >> 4) * 8;
        u32 wp[4];
#pragma unroll
        for (int jj = 0; jj < 4; ++jj) {
            float w0 = wf[(kb + 2 * jj) * DIM + col];
            float w1 = wf[(kb + 2 * jj + 1) * DIM + col];
            wp[jj] = (u32)f2bf(w0) | ((u32)f2bf(w1) << 16);
        }
        wB4[tile * 64 + l] = make_uint4(wp[0], wp[1], wp[2], wp[3]);
    }
    int e0 = blockIdx.x * EB;
    int nval = min(EB, NE - e0);    // valid edges this block
    int4 er[8];
    bool val[8];
#pragma unroll
    for (int k = 0; k < 8; ++k) {
        int idx4 = (e0 >> 2) + k * 256 + t;
        val[k] = idx4 < NE / 4;
        er[k] = val[k] ? erow4[idx4] : make_int4(0, 0, 0, 0);
    }
    for (int i = t; i < 512; i += 256) sa[i] = 0;
    __syncthreads();
#pragma unroll
    for (int k = 0; k < 8; ++k) {
        if (val[k]) {
            atomicAdd(&sa[er[k].x >> 8], 1);
            atomicAdd(&sa[er[k].y >> 8], 1);
            atomicAdd(&sa[er[k].z >> 8], 1);
            atomicAdd(&sa[er[k].w >> 8], 1);
        }
    }
    __syncthreads();
    // reserve global runs (reads sa pre-scan; scan round 1 writes sb only, then syncs)
    for (int i = t; i < NBK; i += 256) base[i] = atomicAdd(&bcur[i], sa[i]);
    // Hillis-Steele inclusive scan over 512 (ping-pong)
    int* pa = sa; int* pb = sb;
    for (int d = 1; d < 512; d <<= 1) {
        for (int i = t; i < 512; i += 256)
            pb[i] = (i >= d) ? (pa[i] + pa[i - d]) : pa[i];
        __syncthreads();
        int* tmp = pa; pa = pb; pb = tmp;
    }
    for (int i = t; i < 512; i += 256) {
        int ex = i ? pa[i - 1] : 0;
        rs[i] = ex;
        if (i < NBK) lcur[i] = ex;
    }
    __syncthreads();
    // LDS scatter (counting-sort placement)
#pragma unroll
    for (int k = 0; k < 8; ++k) {
        if (val[k]) {
            int idx4 = (e0 >> 2) + k * 256 + t;
            int4 c = ecol4[idx4];
            float4 v = ev4[idx4];
            int r, b, pos;
            r = er[k].x; b = r >> 8; pos = atomicAdd(&lcur[b], 1);
            sscv[pos] = ((u32)f2bf(v.x) << 17) | (u32)c.x; skey[pos] = ((u32)b << 8) | (u32)(r & 255);
            r = er[k].y; b = r >> 8; pos = atomicAdd(&lcur[b], 1);
            sscv[pos] = ((u32)f2bf(v.y) << 17) | (u32)c.y; skey[pos] = ((u32)b << 8) | (u32)(r & 255);
            r = er[k].z; b = r >> 8; pos = atomicAdd(&lcur[b], 1);
            sscv[pos] = ((u32)f2bf(v.z) << 17) | (u32)c.z; skey[pos] = ((u32)b << 8) | (u32)(r & 255);
            r = er[k].w; b = r >> 8; pos = atomicAdd(&lcur[b], 1);
            sscv[pos] = ((u32)f2bf(v.w) << 17) | (u32)c.w; skey[pos] = ((u32)b << 8) | (u32)(r & 255);
        }
    }
    __syncthreads();
    // linear copy-out: consecutive i within a run -> consecutive global addresses
    for (int i = t; i < nval; i += 256) {
        u32 key = skey[i];
        int bk = key >> 8;
        int gl = base[bk] + (i - rs[bk]);
        if (gl < BCAP) {
            scv[bk * BCAP + gl] = sscv[i];
            slr[bk * BCAP + gl] = (u8)(key & 255);
        }
    }
}

// ---- csr: inline bucket-base prefix + LDS histogram/scan -> exact offs; LDS scatter ----
__global__ __launch_bounds__(256) void csr_kernel(const u32* __restrict__ scv,
                                                  const u8* __restrict__ slr,
                                                  const int* __restrict__ bcur,
                                                  int* __restrict__ offs,
                                                  u32* __restrict__ cvp) {
    __shared__ u32 lcv[BCAP];       // 36,864 B
    __shared__ int sa[RB], sb[RB], lcur[RB], red[256];
    int b = blockIdx.x, t = threadIdx.x;
    int r0 = b * RB;
    int rows = min(RB, NN - r0);
    int n = min(bcur[b], BCAP);
    // gbase = sum_{i<b} min(bcur[i],BCAP) via strided partials + tree reduce
    int p = 0;
    for (int i = t; i < b; i += 256) p += min(bcur[i], BCAP);
    red[t] = p;
    sa[t] = 0;
    __syncthreads();
    for (int d = 128; d; d >>= 1) {
        if (t < d) red[t] += red[t + d];
        __syncthreads();
    }
    int gbase = red[0];
    if (b == NBK - 1 && t == 0) offs[NN] = gbase + n;
    const u32* scvB = scv + (size_t)b * BCAP;
    const u8* slrB = slr + (size_t)b * BCAP;
    const u32* slr4 = (const u32*)slrB;     // BCAP%4==0, base 16B-aligned
    const uint4* scv4 = (const uint4*)scvB;
    int n4 = n >> 2;
    for (int i = t; i < n4; i += 256) {
        u32 w = slr4[i];
        atomicAdd(&sa[w & 255], 1);
        atomicAdd(&sa[(w >> 8) & 255], 1);
        atomicAdd(&sa[(w >> 16) & 255], 1);
        atomicAdd(&sa[w >> 24], 1);
    }
    for (int i = (n4 << 2) + t; i < n; i += 256) atomicAdd(&sa[slrB[i]], 1);
    __syncthreads();
    int* pa = sa; int* pb = sb;
    for (int d = 1; d < 256; d <<= 1) {
        pb[t] = (t >= d) ? (pa[t] + pa[t - d]) : pa[t];
        __syncthreads();
        int* tmp = pa; pa = pb; pb = tmp;
    }
    int excl = t ? pa[t - 1] : 0;
    if (t < rows) offs[r0 + t] = gbase + excl;
    lcur[t] = excl;
    __syncthreads();
    for (int i = t; i < n4; i += 256) {
        uint4 cvq = scv4[i];
        u32 w = slr4[i];
        int pos;
        pos = atomicAdd(&lcur[w & 255], 1);         lcv[pos] = cvq.x;
        pos = atomicAdd(&lcur[(w >> 8) & 255], 1);  lcv[pos] = cvq.y;
        pos = atomicAdd(&lcur[(w >> 16) & 255], 1); lcv[pos] = cvq.z;
        pos = atomicAdd(&lcur[w >> 24], 1);         lcv[pos] = cvq.w;
    }
    for (int i = (n4 << 2) + t; i < n; i += 256) {
        int pos = atomicAdd(&lcur[slrB[i]], 1);
        lcv[pos] = scvB[i];
    }
    __syncthreads();
    for (int i = t; i < n; i += 256) cvp[gbase + i] = lcv[i];
}

// ---- gemm: support = X @ W, bf16 out (packed u32 pairs), row-major sup[node][64] ----
__global__ __launch_bounds__(256) void gemm_kernel(const float4* __restrict__ xf4,
                                                   const uint4* __restrict__ wB4,
                                                   u32* __restrict__ sup) {
    __shared__ u32 st[64][68];      // 64 rows x 64 col-pairs, +4 pad
    int t = threadIdx.x, wave = t >> 6, lane = t & 63;
    int l15 = lane & 15, kg = lane >> 4;
    int row = blockIdx.x * 64 + wave * 16 + l15;   // A-frag row
    int rc = min(row, NN - 1);
    f32x4 acc[8];
#pragma unroll
    for (int n = 0; n < 8; ++n) acc[n] = (f32x4){0.f, 0.f, 0.f, 0.f};
#pragma unroll
    for (int kt = 0; kt < 4; ++kt) {
        int k0 = kt * 32 + kg * 8;
        int bidx = (rc * DIM + k0) >> 2;
        float4 xa = xf4[bidx];
        float4 xc = xf4[bidx + 1];
        union { u32 u[4]; bf16x8 v; } A;
        A.u[0] = (u32)f2bf(xa.x) | ((u32)f2bf(xa.y) << 16);
        A.u[1] = (u32)f2bf(xa.z) | ((u32)f2bf(xa.w) << 16);
        A.u[2] = (u32)f2bf(xc.x) | ((u32)f2bf(xc.y) << 16);
        A.u[3] = (u32)f2bf(xc.z) | ((u32)f2bf(xc.w) << 16);
#pragma unroll
        for (int n = 0; n < 8; ++n) {
            union { uint4 u; bf16x8 v; } B;
            B.u = wB4[(kt * 8 + n) * 64 + lane];
            acc[n] = __builtin_amdgcn_mfma_f32_16x16x32_bf16(A.v, B.v, acc[n], 0, 0, 0);
        }
    }
    // C layout (m89-verified): col = lane&15, row = (lane>>4)*4 + reg
    u16* stp = (u16*)st;
    int rbase = wave * 16 + kg * 4;
#pragma unroll
    for (int n = 0; n < 8; ++n)
#pragma unroll
        for (int i = 0; i < 4; ++i)
            stp[(rbase + i) * 136 + n * 16 + l15] = f2bf(acc[n][i]);
    __syncthreads();
    int r0 = blockIdx.x * 64;
    int rmax = min(64, NN - r0);
    for (int idx = t; idx < 4096; idx += 256) {
        int r = idx >> 6, c = idx & 63;
        if (r < rmax) sup[(r0 + r) * 64 + c] = st[r][c];
    }
}

// ---- fused: out[r] = sum_e v * support[c] + bias ; wave=node, 2 waves/block ----
// readlane-scalarized edge chain (SALU, EXEC-independent); Q-deep gather batches.
// 2-wave blocks: double workgroup-slot-limited occupancy vs 1-wave blocks.
template <int Q>
__device__ __forceinline__ void gstep(u32 pv, int kk, const u32* __restrict__ sup,
                                      int lane, float& a0, float& a1) {
    u32 ps[Q], xr[Q];
#pragma unroll
    for (int q = 0; q < Q; ++q)
        ps[q] = (u32)__builtin_amdgcn_readlane((int)pv, kk + q);
#pragma unroll
    for (int q = 0; q < Q; ++q)
        xr[q] = __hip_atomic_load(sup + ((ps[q] & 0x1ffffu) << 6) + lane,
                                  __ATOMIC_RELAXED, __HIP_MEMORY_SCOPE_AGENT);
#pragma unroll
    for (int q = 0; q < Q; ++q) {
        float v = bflo(ps[q] >> 17);
        a0 = fmaf(v, bflo(xr[q]), a0);
        a1 = fmaf(v, bfhi(xr[q]), a1);
    }
}

__global__ __launch_bounds__(128) void fused_kernel(const int* __restrict__ offs,
                                                    const u32* __restrict__ cvp,
                                                    const u32* __restrict__ sup,
                                                    const float2* __restrict__ bf2v,
                                                    u64* __restrict__ out) {
    int t = threadIdx.x;
    int wave = t >> 6, lane = t & 63;
    int gw = blockIdx.x * 2 + wave;     // NN even; grid = NN/2
    int start = offs[gw];
    int end = offs[gw + 1];
    int cnt = end - start;
    float2 bp = bf2v[lane];
    float a0 = bp.x, a1 = bp.y;
    for (int j = 0; j < cnt; j += 64) {
        u32 pv = (j + lane < cnt) ? __builtin_nontemporal_load(&cvp[start + j + lane]) : 0u;
        int rem = min(64, cnt - j);
        int kk = 0;
        for (; kk + 32 <= rem; kk += 32) gstep<32>(pv, kk, sup, lane, a0, a1);
        for (; kk < rem; kk += 8) gstep<8>(pv, kk, sup, lane, a0, a1);
    }
    u64 bits = (u64)__float_as_uint(a0) | ((u64)__float_as_uint(a1) << 32);
    __builtin_nontemporal_store(bits, &out[(size_t)gw * 64 + lane]);
}

extern "C" void kernel_launch(void* const* d_in, const int* in_sizes, int n_in,
                              void* d_out, int out_size, void* d_ws, size_t ws_size,
                              hipStream_t stream) {
    const float* x = (const float*)d_in[0];
    const int* erow = (const int*)d_in[1];
    const int* ecol = (const int*)d_in[2];
    const float* ev = (const float*)d_in[3];
    const float* wf = (const float*)d_in[4];
    const float2* bf2v = (const float2*)d_in[5];

    char* ws = (char*)d_ws;
    int* offs = (int*)(ws + OFF_OFFS);
    uint4* wB4 = (uint4*)(ws + OFF_WB);
    int* bcur = (int*)(ws + OFF_BCUR);
    u32* cvp = (u32*)(ws + OFF_CVP);
    u32* scv = (u32*)(ws + OFF_SH);
    u8* slr = (u8*)(ws + OFF_SH + SCV_BYTES);
    u32* sup = (u32*)(ws + OFF_SH);   // overlays staging after csr is done

    hipMemsetAsync(bcur, 0, NBK * sizeof(int), stream);

    bin_kernel<<<(NE + EB - 1) / EB, 256, 0, stream>>>((const int4*)erow, (const int4*)ecol,
                                                       (const float4*)ev, bcur,
                                                       scv, slr, wf, wB4);
    csr_kernel<<<NBK, 256, 0, stream>>>(scv, slr, bcur, offs, cvp);
    gemm_kernel<<<(NN + 63) / 64, 256, 0, stream>>>((const float4*)x, wB4, sup);
    fused_kernel<<<NN / 2, 128, 0, stream>>>(offs, cvp, sup, bf2v, (u64*)d_out);
}